// Round 3
// baseline (208.032 us; speedup 1.0000x reference)
//
#include <hip/hip_runtime.h>
#include <math.h>

// Problem constants
#define BZ      64
#define NC      2048
#define HH      14
#define HW      196        // 14*14
#define NCLS    1000
#define SPLITS  8
#define CPB     (NC/SPLITS)   // 256 channels per block
#define CHUNK   8
#define NCHUNK  (CPB/CHUNK)   // 32
#define LPAD    200           // padded channel stride in LDS (floats)
#define NTRI    105           // 14*15/2 upper-triangle entries of G

// ws layout (floats / 4-byte words)
#define CAM_OFF  0                                  // [64][8][3][196]
#define G_OFF    (BZ*SPLITS*3*HW)                   // [64][8][196] (first 105 used)
#define S_OFF    (G_OFF + BZ*SPLITS*HW)             // [64][8][14]
#define CE_OFF   (S_OFF + BZ*SPLITS*HH)             // [64] floats
#define TICK_OFF (CE_OFF + BZ)                      // [64] ints

// block reduce over 256 threads: MODE 0=sum, 1=min, 2=max; broadcast result
template<int MODE>
__device__ __forceinline__ float bred(float v, float* red){
  #pragma unroll
  for (int o=32;o>0;o>>=1){
    float u = __shfl_down(v, o, 64);
    if (MODE==0) v += u; else if (MODE==1) v = fminf(v,u); else v = fmaxf(v,u);
  }
  __syncthreads();
  if ((threadIdx.x & 63)==0) red[threadIdx.x>>6] = v;
  __syncthreads();
  float r = red[0];
  #pragma unroll
  for (int w=1;w<4;w++){
    float u = red[w];
    if (MODE==0) r += u; else if (MODE==1) r = fminf(r,u); else r = fmaxf(r,u);
  }
  return r;
}

// ---------------------------------------------------------------------------
// Init kernel: one block per batch. Zero the per-batch ticket (ws is poisoned
// by the harness each iteration) and compute the logsumexp cross-entropy for
// this batch (depends only on pred -> fully off the main critical path).
// Kernel-boundary release/acquire makes these visible to k_main.
// ---------------------------------------------------------------------------
__global__ __launch_bounds__(256) void k_init(
    const float* __restrict__ pred, const int* __restrict__ cla,
    float* __restrict__ ws)
{
  const int t = threadIdx.x, b = blockIdx.x;
  __shared__ float red[4];
  if (t == 0) ((int*)ws)[TICK_OFF + b] = 0;

  const float* pb = pred + (size_t)b*NCLS;
  float mv = -3.0e38f;
  for (int i=t;i<NCLS;i+=256) mv = fmaxf(mv, pb[i]);
  mv = bred<2>(mv, red);
  float es = 0.f;
  for (int i=t;i<NCLS;i+=256) es += expf(pb[i]-mv);
  es = bred<0>(es, red);
  if (t==0){
    float lse = mv + logf(es);
    ws[CE_OFF + b] = lse - pb[cla[b]];
  }
}

// ---------------------------------------------------------------------------
// Main kernel, grid (SPLITS, BZ), 256 threads.
// Phase A (validated round-1 structure): stage F chunks global->reg->LDS
//   (depth-1 prefetch, double-buffered); Gram column outer products (t<112,
//   register triangle acc[105]); CAM partials + spatial sums (128<=t<177).
//   Partials stored to ws.
// Last-arriver: __threadfence (release: L2 writeback to shared L3) +
//   atomicAdd(ticket[b]). The 8th arriver for batch b does phase B inline:
//   __threadfence (acquire: L2 invalidate), volatile reads of the 8 split
//   partials, normalize/ed1/quadratic forms, then atomicAdd(out, term/64).
//   Deadlock-free: no block ever waits on another.
// ---------------------------------------------------------------------------
__global__ __launch_bounds__(256) void k_main(
    const float* __restrict__ F, const float* __restrict__ W,
    const int* __restrict__ idx, const float* __restrict__ seg,
    float* __restrict__ ws, float* __restrict__ out)
{
  __shared__ __align__(16) float Fs[2][CHUNK*LPAD];   // 12.8 KB
  __shared__ __align__(16) float wls[3][CPB];         // 3 KB
  __shared__ __align__(16) float sred[HW];            // 0.78 KB
  __shared__ int lastFlag;
  __shared__ __align__(16) union Ovl {
    float gacc[112*NTRI];                             // 47 KB (phase A)
    struct {
      float cam[3][HW]; float Gt[NTRI]; float Sv[HH];
      float D1[HW]; float D2[HW]; float EE[HW];
      float rowv[HH]; float dc1[HH]; float dc2[HH];
      float red[4]; float scal[6];
    } p2;                                             // 5.3 KB (phase B)
  } U;

  const int t = threadIdx.x;
  const int s = blockIdx.x;     // split
  const int b = blockIdx.y;     // batch
  const int cbase = s*CPB;

  // ---------------- Phase A ----------------
  {
    const int i0 = idx[b*3+0], i1 = idx[b*3+1], i2 = idx[b*3+2];
    // CPB == 256 == blockDim
    wls[0][t] = W[(size_t)i0*NC + cbase + t];
    wls[1][t] = W[(size_t)i1*NC + cbase + t];
    wls[2][t] = W[(size_t)i2*NC + cbase + t];

    const float4* Fb4 = (const float4*)(F + ((size_t)b*NC + cbase)*HW);

    const bool isG   = (t < 112);
    const int  cL    = t & 7;        // channel-in-chunk
    const int  jc    = t >> 3;       // column 0..13
    const bool isCam = (t >= 128 && t < 177);
    const int  cp    = t - 128;
    const bool isLd  = (t < 196);    // 196 threads x 2 float4 = 392 = chunk

    float acc[NTRI];
    #pragma unroll
    for (int k=0;k<NTRI;k++) acc[k]=0.f;
    float4 c0a = make_float4(0.f,0.f,0.f,0.f);
    float4 c1a = make_float4(0.f,0.f,0.f,0.f);
    float4 c2a = make_float4(0.f,0.f,0.f,0.f);
    float4 sA  = make_float4(0.f,0.f,0.f,0.f);

    float4 p0, p1;
    auto loadChunk = [&](int ch){
      if (isLd){
        const float4* src = Fb4 + (size_t)ch*392;
        p0 = src[2*t]; p1 = src[2*t+1];
      }
    };
    auto storeChunk = [&](int bufi){
      if (isLd){
        float4* dst = (float4*)(&Fs[bufi][0]);
        int i = 2*t;   dst[(i/49)*(LPAD/4) + (i%49)] = p0;
        i = 2*t+1;     dst[(i/49)*(LPAD/4) + (i%49)] = p1;
      }
    };

    loadChunk(0);
    storeChunk(0);
    __syncthreads();

    #pragma unroll 1
    for (int ch = 0; ch < NCHUNK; ++ch){
      const int bufi = ch & 1;
      if (ch+1 < NCHUNK) loadChunk(ch+1);   // prefetch next slab into regs
      const float* Fsb = &Fs[bufi][0];

      if (isG){
        const float* colp = Fsb + cL*LPAD + jc;
        float x[14];
        #pragma unroll
        for (int m=0;m<14;m++) x[m] = colp[m*HH];
        #pragma unroll
        for (int m=0;m<14;m++){
          #pragma unroll
          for (int n=m;n<14;n++){
            acc[14*m - (m*(m-1))/2 + (n-m)] += x[m]*x[n];
          }
        }
      }
      if (isCam){
        float w0a[CHUNK], w1a[CHUNK], w2a[CHUNK];
        *(float4*)&w0a[0] = *(const float4*)&wls[0][ch*CHUNK];
        *(float4*)&w0a[4] = *(const float4*)&wls[0][ch*CHUNK+4];
        *(float4*)&w1a[0] = *(const float4*)&wls[1][ch*CHUNK];
        *(float4*)&w1a[4] = *(const float4*)&wls[1][ch*CHUNK+4];
        *(float4*)&w2a[0] = *(const float4*)&wls[2][ch*CHUNK];
        *(float4*)&w2a[4] = *(const float4*)&wls[2][ch*CHUNK+4];
        #pragma unroll
        for (int c=0;c<CHUNK;c++){
          float4 v = *(const float4*)(Fsb + c*LPAD + 4*cp);
          c0a.x += w0a[c]*v.x; c0a.y += w0a[c]*v.y; c0a.z += w0a[c]*v.z; c0a.w += w0a[c]*v.w;
          c1a.x += w1a[c]*v.x; c1a.y += w1a[c]*v.y; c1a.z += w1a[c]*v.z; c1a.w += w1a[c]*v.w;
          c2a.x += w2a[c]*v.x; c2a.y += w2a[c]*v.y; c2a.z += w2a[c]*v.z; c2a.w += w2a[c]*v.w;
          sA.x += v.x; sA.y += v.y; sA.z += v.z; sA.w += v.w;
        }
      }
      if (ch+1 < NCHUNK) storeChunk((ch+1)&1);
      __syncthreads();
    }

    // ---- phase A epilogue ----
    const size_t pslot = (size_t)(b*SPLITS + s);
    if (isCam){
      float* base = ws + CAM_OFF + pslot*3*HW;
      *(float4*)(base          + 4*cp) = c0a;
      *(float4*)(base + HW     + 4*cp) = c1a;
      *(float4*)(base + 2*HW   + 4*cp) = c2a;
      *(float4*)(sred + 4*cp) = sA;
    }
    if (isG){
      float* gr = &U.gacc[t*NTRI];
      #pragma unroll
      for (int k=0;k<NTRI;k++) gr[k] = acc[k];
    }
    __syncthreads();

    if (t < NTRI){
      float a = 0.f;
      for (int th=0; th<112; th++) a += U.gacc[th*NTRI + t];
      ws[G_OFF + pslot*HW + t] = a;
    }
    if (t >= 128 && t < 128+HH){
      int r = t - 128;
      float a = 0.f;
      #pragma unroll
      for (int j=0;j<HH;j++) a += sred[r*HH+j];
      ws[S_OFF + pslot*HH + r] = a;
    }
    __syncthreads();   // gacc reads done before union reuse in phase B
  }

  // ---------------- last-arriver handoff ----------------
  if (t == 0){
    __threadfence();   // release: drain stores, write back L2 to shared L3
    int old = atomicAdd(&((int*)ws)[TICK_OFF + b], 1);
    lastFlag = (old == SPLITS-1) ? 1 : 0;
    __threadfence();   // acquire: invalidate L2 so later loads see L3
  }
  __syncthreads();

  // ---------------- Phase B (last arriver only) ----------------
  if (lastFlag){
    volatile const float* vws = (volatile const float*)ws;

    // reduce split partials
    if (t < HW){
      for (int k=0;k<3;k++){
        float a=0.f;
        for (int sp=0;sp<SPLITS;sp++)
          a += vws[CAM_OFF + ((size_t)(b*SPLITS+sp)*3 + k)*HW + t];
        U.p2.cam[k][t]=a;
      }
    }
    if (t < NTRI){
      float g=0.f;
      for (int sp=0;sp<SPLITS;sp++) g += vws[G_OFF + (size_t)(b*SPLITS+sp)*HW + t];
      U.p2.Gt[t]=g;
    }
    if (t < HH){
      float a=0.f;
      for (int sp=0;sp<SPLITS;sp++) a += vws[S_OFF + (size_t)(b*SPLITS+sp)*HH + t];
      U.p2.Sv[t]=a;
    }
    __syncthreads();

    // per-cam min/max
    for (int k=0;k<3;k++){
      float v = (t<HW)? U.p2.cam[k][t] : 3.0e38f;
      float mn = bred<1>(v, U.p2.red);
      v = (t<HW)? U.p2.cam[k][t] : -3.0e38f;
      float mx = bred<2>(v, U.p2.red);
      if (t==0){ U.p2.scal[2*k]=mn; U.p2.scal[2*k+1]=mx; }
    }
    __syncthreads();

    // normalize, dst, D, EE
    if (t < HW){
      float c0 = (U.p2.cam[0][t]-U.p2.scal[0]) / (U.p2.scal[1]-U.p2.scal[0]) * 255.0f;
      float c1 = (U.p2.cam[1][t]-U.p2.scal[2]) / (U.p2.scal[3]-U.p2.scal[2]) * 255.0f;
      float c2 = (U.p2.cam[2][t]-U.p2.scal[4]) / (U.p2.scal[5]-U.p2.scal[4]) * 255.0f;
      float dst = (c0 > 125.0f) ? 1.0f : 0.0f;
      U.p2.D1[t] = c0 - c1; U.p2.D2[t] = c0 - c2;
      float e = dst - seg[(size_t)b*HW + t] + 1e-6f;
      U.p2.EE[t] = e*e;
    }
    __syncthreads();

    if (t < HH){
      float rs=0.f, d1=0.f, d2=0.f;
      #pragma unroll
      for (int j=0;j<HH;j++){
        rs += U.p2.EE[t*HH+j];
        d1 += U.p2.D1[j*HH+t];
        d2 += U.p2.D2[j*HH+t];
      }
      U.p2.rowv[t] = sqrtf(rs); U.p2.dc1[t]=d1; U.p2.dc2[t]=d2;
    }
    __syncthreads();

    // H[m,m'] * G[m,m'] summed (G from triangle by symmetry)
    float v1=0.f, v2=0.f;
    if (t < HW){
      int m = t/HH, mp = t%HH;
      float h1=0.f, h2=0.f;
      #pragma unroll
      for (int i=0;i<HH;i++){
        h1 += U.p2.D1[i*HH+m]*U.p2.D1[i*HH+mp];
        h2 += U.p2.D2[i*HH+m]*U.p2.D2[i*HH+mp];
      }
      int mm = (m<mp)?m:mp, nn = (m<mp)?mp:m;
      float g = U.p2.Gt[14*mm - (mm*(mm-1))/2 + (nn-mm)];
      v1 = h1*g; v2 = h2*g;
    }
    float sx2_1 = bred<0>(v1, U.p2.red);
    float sx2_2 = bred<0>(v2, U.p2.red);

    if (t==0){
      float ce = vws[CE_OFF + b];
      float ed1 = 0.f;
      #pragma unroll
      for (int i=0;i<HH;i++) ed1 += U.p2.rowv[i];
      ed1 *= (1.0f/14.0f);
      float sx1=0.f, sx2=0.f;
      #pragma unroll
      for (int m=0;m<HH;m++){ sx1 += U.p2.dc1[m]*U.p2.Sv[m]; sx2 += U.p2.dc2[m]*U.p2.Sv[m]; }
      const float NEPS2 = 401408.0f * 1e-12f;
      float d01 = sqrtf(sx2_1 + 2e-6f*sx1 + NEPS2) * (1.0f/2048.0f);
      float d02 = sqrtf(sx2_2 + 2e-6f*sx2 + NEPS2) * (1.0f/2048.0f);
      float term = ed1 + fmaxf(0.0f, 70.0f - d01 - d02) + ce;
      atomicAdd(out, term * (1.0f/64.0f));
    }
  }
}

extern "C" void kernel_launch(void* const* d_in, const int* in_sizes, int n_in,
                              void* d_out, int out_size, void* d_ws, size_t ws_size,
                              hipStream_t stream) {
  const float* pred = (const float*)d_in[0];
  const int*   cla  = (const int*)  d_in[1];
  const float* seg  = (const float*)d_in[2];
  const float* F    = (const float*)d_in[3];
  const float* W    = (const float*)d_in[4];
  const int*   idx  = (const int*)  d_in[5];
  float* out = (float*)d_out;
  float* ws  = (float*)d_ws;

  k_init<<<BZ, 256, 0, stream>>>(pred, cla, ws);
  k_main<<<dim3(SPLITS, BZ), 256, 0, stream>>>(F, W, idx, seg, ws, out);
}

// Round 4
// 207.278 us; speedup vs baseline: 1.0036x; 1.0036x over previous
//
#include <hip/hip_runtime.h>
#include <math.h>

// Problem constants
#define BZ      64
#define NC      2048
#define HH      14
#define HW      196        // 14*14
#define NCLS    1000
#define SPLITS  8
#define CPB     (NC/SPLITS)   // 256 channels per block
#define CHUNK   8
#define NCHUNK  (CPB/CHUNK)   // 32
#define LPAD    200           // padded channel stride in LDS (floats)
#define NTRI    105           // 14*15/2 upper-triangle entries of G
#define KSPL    53            // triangle split: [0,53) / [53,105)

// ws layout (floats / 4-byte words)
#define CAM_OFF  0                                  // [64][8][3][196]
#define G_OFF    (BZ*SPLITS*3*HW)                   // [64][8][196] (first 105 used)
#define S_OFF    (G_OFF + BZ*SPLITS*HW)             // [64][8][14]
#define CE_OFF   (S_OFF + BZ*SPLITS*HH)             // [64] floats
#define TICK_OFF (CE_OFF + BZ)                      // [64] ints

// block reduce over 256 threads: MODE 0=sum, 1=min, 2=max; broadcast result
template<int MODE>
__device__ __forceinline__ float bred(float v, float* red){
  #pragma unroll
  for (int o=32;o>0;o>>=1){
    float u = __shfl_down(v, o, 64);
    if (MODE==0) v += u; else if (MODE==1) v = fminf(v,u); else v = fmaxf(v,u);
  }
  __syncthreads();
  if ((threadIdx.x & 63)==0) red[threadIdx.x>>6] = v;
  __syncthreads();
  float r = red[0];
  #pragma unroll
  for (int w=1;w<4;w++){
    float u = red[w];
    if (MODE==0) r += u; else if (MODE==1) r = fminf(r,u); else r = fmaxf(r,u);
  }
  return r;
}

// Gram column outer-product step for triangle entries k in [LO,HI).
// Compile-time LO/HI -> static acc indexing (no scratch), unused x[] loads DCE.
template<int LO, int HI>
__device__ __forceinline__ void gramStep(const float* __restrict__ colp,
                                         float* __restrict__ acc){
  float x[14];
  #pragma unroll
  for (int m=0;m<14;m++) x[m] = colp[m*HH];
  #pragma unroll
  for (int m=0;m<14;m++){
    #pragma unroll
    for (int n=m;n<14;n++){
      const int k = 14*m - (m*(m-1))/2 + (n-m);
      if (k >= LO && k < HI) acc[k-LO] += x[m]*x[n];
    }
  }
}

// ---------------------------------------------------------------------------
// Init kernel: one block per batch. Zero the per-batch ticket (ws is poisoned
// each iteration) and compute the logsumexp cross-entropy for this batch.
// ---------------------------------------------------------------------------
__global__ __launch_bounds__(256) void k_init(
    const float* __restrict__ pred, const int* __restrict__ cla,
    float* __restrict__ ws)
{
  const int t = threadIdx.x, b = blockIdx.x;
  __shared__ float red[4];
  if (t == 0) ((int*)ws)[TICK_OFF + b] = 0;

  const float* pb = pred + (size_t)b*NCLS;
  float mv = -3.0e38f;
  for (int i=t;i<NCLS;i+=256) mv = fmaxf(mv, pb[i]);
  mv = bred<2>(mv, red);
  float es = 0.f;
  for (int i=t;i<NCLS;i+=256) es += expf(pb[i]-mv);
  es = bred<0>(es, red);
  if (t==0){
    float lse = mv + logf(es);
    ws[CE_OFF + b] = lse - pb[cla[b]];
  }
}

// ---------------------------------------------------------------------------
// Main kernel, grid (SPLITS, BZ), 256 threads, min 2 waves/EU (=> 256 VGPR
// budget, no accumulator spill; LDS 64.1KB -> 2 blocks/CU).
// Phase A: stage F chunks global->reg->LDS (double-buffered).
//   Gram: wave-aligned triangle split. Waves 0-1 (t<112): pair cc=t,
//     entries [0,53). Waves 2-3 (128<=t<240): pair cc=t-128, entries
//     [53,105). acc fits registers (53 floats).
//   CAM: thread t<196 owns position t (stride-1 LDS reads, 2-way alias =
//     free; w loads wave-uniform broadcast). Uniform across waves.
// Last-arriver: threadfence + atomicAdd(ticket[b]); 8th arriver does phase B
//   inline and atomicAdds its term/64 into out (harness zeroes out).
// ---------------------------------------------------------------------------
__global__ __launch_bounds__(256, 2) void k_main(
    const float* __restrict__ F, const float* __restrict__ W,
    const int* __restrict__ idx, const float* __restrict__ seg,
    float* __restrict__ ws, float* __restrict__ out)
{
  __shared__ __align__(16) float Fs[2][CHUNK*LPAD];   // 12.8 KB
  __shared__ __align__(16) float wls[3][CPB];         // 3 KB
  __shared__ __align__(16) float sred[HW];            // 0.78 KB
  __shared__ int lastFlag;
  __shared__ __align__(16) union Ovl {
    float gacc[224*KSPL];                             // 47.5 KB (phase A)
    struct {
      float cam[3][HW]; float Gt[NTRI]; float Sv[HH];
      float D1[HW]; float D2[HW]; float EE[HW];
      float rowv[HH]; float dc1[HH]; float dc2[HH];
      float red[4]; float scal[6];
    } p2;                                             // 5.3 KB (phase B)
  } U;

  const int t = threadIdx.x;
  const int s = blockIdx.x;     // split
  const int b = blockIdx.y;     // batch
  const int cbase = s*CPB;

  // Gram team: 0 = waves 0-1 (t<112), 1 = waves 2-3 (128<=t<240)
  const int gteam = (t < 112) ? 0 : ((t >= 128 && t < 240) ? 1 : -1);
  const int cc    = (t < 128) ? t : (t - 128);   // pair index 0..111 (when valid)
  const int cL    = cc & 7;        // channel-in-chunk
  const int jc    = cc >> 3;       // column 0..13
  const bool isCam = (t < 196);    // CAM position t
  const bool isLd  = (t < 196);    // 196 threads x 2 float4 = 392 = chunk

  // ---------------- Phase A ----------------
  {
    const int i0 = idx[b*3+0], i1 = idx[b*3+1], i2 = idx[b*3+2];
    // CPB == 256 == blockDim
    wls[0][t] = W[(size_t)i0*NC + cbase + t];
    wls[1][t] = W[(size_t)i1*NC + cbase + t];
    wls[2][t] = W[(size_t)i2*NC + cbase + t];

    const float4* Fb4 = (const float4*)(F + ((size_t)b*NC + cbase)*HW);

    float acc[KSPL];
    #pragma unroll
    for (int k=0;k<KSPL;k++) acc[k]=0.f;
    float cam0=0.f, cam1=0.f, cam2=0.f, ssum=0.f;

    float4 p0, p1;
    auto loadChunk = [&](int ch){
      if (isLd){
        const float4* src = Fb4 + (size_t)ch*392;
        p0 = src[2*t]; p1 = src[2*t+1];
      }
    };
    auto storeChunk = [&](int bufi){
      if (isLd){
        float4* dst = (float4*)(&Fs[bufi][0]);
        int i = 2*t;   dst[(i/49)*(LPAD/4) + (i%49)] = p0;
        i = 2*t+1;     dst[(i/49)*(LPAD/4) + (i%49)] = p1;
      }
    };

    loadChunk(0);
    storeChunk(0);
    __syncthreads();

    #pragma unroll 1
    for (int ch = 0; ch < NCHUNK; ++ch){
      const int bufi = ch & 1;
      if (ch+1 < NCHUNK) loadChunk(ch+1);   // prefetch next slab into regs
      const float* Fsb = &Fs[bufi][0];

      if (gteam == 0){
        gramStep<0,KSPL>(Fsb + cL*LPAD + jc, acc);
      } else if (gteam == 1){
        gramStep<KSPL,NTRI>(Fsb + cL*LPAD + jc, acc);
      }
      if (isCam){
        float w0a[CHUNK], w1a[CHUNK], w2a[CHUNK];   // wave-uniform broadcasts
        *(float4*)&w0a[0] = *(const float4*)&wls[0][ch*CHUNK];
        *(float4*)&w0a[4] = *(const float4*)&wls[0][ch*CHUNK+4];
        *(float4*)&w1a[0] = *(const float4*)&wls[1][ch*CHUNK];
        *(float4*)&w1a[4] = *(const float4*)&wls[1][ch*CHUNK+4];
        *(float4*)&w2a[0] = *(const float4*)&wls[2][ch*CHUNK];
        *(float4*)&w2a[4] = *(const float4*)&wls[2][ch*CHUNK+4];
        #pragma unroll
        for (int c=0;c<CHUNK;c++){
          float v = Fsb[c*LPAD + t];
          cam0 += w0a[c]*v; cam1 += w1a[c]*v; cam2 += w2a[c]*v; ssum += v;
        }
      }
      if (ch+1 < NCHUNK) storeChunk((ch+1)&1);
      __syncthreads();
    }

    // ---- phase A epilogue ----
    const size_t pslot = (size_t)(b*SPLITS + s);
    if (isCam){
      float* base = ws + CAM_OFF + pslot*3*HW;
      base[t]        = cam0;
      base[HW + t]   = cam1;
      base[2*HW + t] = cam2;
      sred[t] = ssum;
    }
    if (gteam == 0){
      float* gr = &U.gacc[(size_t)cc*KSPL];
      #pragma unroll
      for (int k=0;k<KSPL;k++) gr[k] = acc[k];
    } else if (gteam == 1){
      float* gr = &U.gacc[(size_t)(112+cc)*KSPL];
      #pragma unroll
      for (int k=0;k<NTRI-KSPL;k++) gr[k] = acc[k];
    }
    __syncthreads();

    if (t < NTRI){
      float a = 0.f;
      if (t < KSPL){
        for (int r=0; r<112; r++)   a += U.gacc[(size_t)r*KSPL + t];
      } else {
        for (int r=112; r<224; r++) a += U.gacc[(size_t)r*KSPL + (t-KSPL)];
      }
      ws[G_OFF + pslot*HW + t] = a;
    }
    if (t >= 128 && t < 128+HH){
      int r = t - 128;
      float a = 0.f;
      #pragma unroll
      for (int j=0;j<HH;j++) a += sred[r*HH+j];
      ws[S_OFF + pslot*HH + r] = a;
    }
    __syncthreads();   // gacc reads done before union reuse in phase B
  }

  // ---------------- last-arriver handoff ----------------
  if (t == 0){
    __threadfence();   // release: drain stores, write back L2 to shared L3
    int old = atomicAdd(&((int*)ws)[TICK_OFF + b], 1);
    lastFlag = (old == SPLITS-1) ? 1 : 0;
    __threadfence();   // acquire: invalidate L2 so later loads see L3
  }
  __syncthreads();

  // ---------------- Phase B (last arriver only) ----------------
  if (lastFlag){
    volatile const float* vws = (volatile const float*)ws;

    // reduce split partials
    if (t < HW){
      for (int k=0;k<3;k++){
        float a=0.f;
        for (int sp=0;sp<SPLITS;sp++)
          a += vws[CAM_OFF + ((size_t)(b*SPLITS+sp)*3 + k)*HW + t];
        U.p2.cam[k][t]=a;
      }
    }
    if (t < NTRI){
      float g=0.f;
      for (int sp=0;sp<SPLITS;sp++) g += vws[G_OFF + (size_t)(b*SPLITS+sp)*HW + t];
      U.p2.Gt[t]=g;
    }
    if (t < HH){
      float a=0.f;
      for (int sp=0;sp<SPLITS;sp++) a += vws[S_OFF + (size_t)(b*SPLITS+sp)*HH + t];
      U.p2.Sv[t]=a;
    }
    __syncthreads();

    // per-cam min/max
    for (int k=0;k<3;k++){
      float v = (t<HW)? U.p2.cam[k][t] : 3.0e38f;
      float mn = bred<1>(v, U.p2.red);
      v = (t<HW)? U.p2.cam[k][t] : -3.0e38f;
      float mx = bred<2>(v, U.p2.red);
      if (t==0){ U.p2.scal[2*k]=mn; U.p2.scal[2*k+1]=mx; }
    }
    __syncthreads();

    // normalize, dst, D, EE
    if (t < HW){
      float c0 = (U.p2.cam[0][t]-U.p2.scal[0]) / (U.p2.scal[1]-U.p2.scal[0]) * 255.0f;
      float c1 = (U.p2.cam[1][t]-U.p2.scal[2]) / (U.p2.scal[3]-U.p2.scal[2]) * 255.0f;
      float c2 = (U.p2.cam[2][t]-U.p2.scal[4]) / (U.p2.scal[5]-U.p2.scal[4]) * 255.0f;
      float dst = (c0 > 125.0f) ? 1.0f : 0.0f;
      U.p2.D1[t] = c0 - c1; U.p2.D2[t] = c0 - c2;
      float e = dst - seg[(size_t)b*HW + t] + 1e-6f;
      U.p2.EE[t] = e*e;
    }
    __syncthreads();

    if (t < HH){
      float rs=0.f, d1=0.f, d2=0.f;
      #pragma unroll
      for (int j=0;j<HH;j++){
        rs += U.p2.EE[t*HH+j];
        d1 += U.p2.D1[j*HH+t];
        d2 += U.p2.D2[j*HH+t];
      }
      U.p2.rowv[t] = sqrtf(rs); U.p2.dc1[t]=d1; U.p2.dc2[t]=d2;
    }
    __syncthreads();

    // H[m,m'] * G[m,m'] summed (G from triangle by symmetry)
    float v1=0.f, v2=0.f;
    if (t < HW){
      int m = t/HH, mp = t%HH;
      float h1=0.f, h2=0.f;
      #pragma unroll
      for (int i=0;i<HH;i++){
        h1 += U.p2.D1[i*HH+m]*U.p2.D1[i*HH+mp];
        h2 += U.p2.D2[i*HH+m]*U.p2.D2[i*HH+mp];
      }
      int mm = (m<mp)?m:mp, nn = (m<mp)?mp:m;
      float g = U.p2.Gt[14*mm - (mm*(mm-1))/2 + (nn-mm)];
      v1 = h1*g; v2 = h2*g;
    }
    float sx2_1 = bred<0>(v1, U.p2.red);
    float sx2_2 = bred<0>(v2, U.p2.red);

    if (t==0){
      float ce = vws[CE_OFF + b];
      float ed1 = 0.f;
      #pragma unroll
      for (int i=0;i<HH;i++) ed1 += U.p2.rowv[i];
      ed1 *= (1.0f/14.0f);
      float sx1=0.f, sx2=0.f;
      #pragma unroll
      for (int m=0;m<HH;m++){ sx1 += U.p2.dc1[m]*U.p2.Sv[m]; sx2 += U.p2.dc2[m]*U.p2.Sv[m]; }
      const float NEPS2 = 401408.0f * 1e-12f;
      float d01 = sqrtf(sx2_1 + 2e-6f*sx1 + NEPS2) * (1.0f/2048.0f);
      float d02 = sqrtf(sx2_2 + 2e-6f*sx2 + NEPS2) * (1.0f/2048.0f);
      float term = ed1 + fmaxf(0.0f, 70.0f - d01 - d02) + ce;
      atomicAdd(out, term * (1.0f/64.0f));
    }
  }
}

extern "C" void kernel_launch(void* const* d_in, const int* in_sizes, int n_in,
                              void* d_out, int out_size, void* d_ws, size_t ws_size,
                              hipStream_t stream) {
  const float* pred = (const float*)d_in[0];
  const int*   cla  = (const int*)  d_in[1];
  const float* seg  = (const float*)d_in[2];
  const float* F    = (const float*)d_in[3];
  const float* W    = (const float*)d_in[4];
  const int*   idx  = (const int*)  d_in[5];
  float* out = (float*)d_out;
  float* ws  = (float*)d_ws;

  k_init<<<BZ, 256, 0, stream>>>(pred, cla, ws);
  k_main<<<dim3(SPLITS, BZ), 256, 0, stream>>>(F, W, idx, seg, ws, out);
}